// Round 7
// baseline (1625.084 us; speedup 1.0000x reference)
//
#include <hip/hip_runtime.h>
#include <hip/hip_bf16.h>

// Problem constants (from reference)
#define IN_PER_SIDE   40960
#define IN_TOTAL      81920     // 2 * 40960
#define L1            512
#define L2            32
#define L3_           32
#define BATCH         4096
#define MAXIDX        128       // per-row index capacity (~60 used)
#define NTILES        10240     // (81920/64) * (512/64) transpose tiles

// clang-native vectors (HIP float4 is a class; builtins reject it)
typedef float    v4f __attribute__((ext_vector_type(4)));
typedef float    v8f __attribute__((ext_vector_type(8)));
typedef _Float16 v4h __attribute__((ext_vector_type(4)));
typedef _Float16 v8h __attribute__((ext_vector_type(8)));

// WT stored as fp16: 81920 * 512 * 2 B = 83.9 MB. |W_in| <= 0.0035 ->
// fp16 storage error gives output absmax ~1.2e-4 (measured R6), thr 4.6e-4.
#define WT_BYTES ((size_t)IN_TOTAL * L1 * sizeof(_Float16))
#define CTR_BYTES 128

// ---------------------------------------------------------------------------
// Single merged kernel, one block per batch row, 512 threads.
//   Phase 0 (work-stolen transpose): blocks claim 64x64 tiles of
//       W_in [512,81920] f32 -> WTh [81920,512] f16 from a global atomic
//       counter until exhausted. Only the first-resident ~1024 blocks get
//       tiles (~10 each); their tile work overlaps other blocks' scans.
//       Completion published via __threadfence() + done-counter (device
//       scope) — the G16 cross-XCD pattern.
//   Phase 1 (scan): nontemporal float4 stream of both feature rows; {0,1}
//       values -> sum test rejects all-zero vectors with one compare.
//   Phase 1.5 (wait): t0 spins until done==NTILES (expected already true
//       after the ~213 us scan), __threadfence() to invalidate stale
//       L1/L2 before reading WTh. Deadlock-free: tiles are completed by
//       resident blocks only, no cross-block dependency in phase 0.
//   Phase 2 (gather): 8 waves x 64 lanes; one feature = 512 fp16 = 1 KB =
//       ONE wave64 x 16 B coalesced load (L3-resident). fp32 accumulate;
//       cross-wave reduce via pad-9 LDS (all accesses <=2-way = free).
//   Phase 3-5: tiny dense layers, shuffle reductions, no atomics.
// ---------------------------------------------------------------------------
__global__ __launch_bounds__(512) void nnue_all(
    const float* __restrict__ W, _Float16* __restrict__ WTh,
    int* __restrict__ ctrs,
    const float* __restrict__ wf, const float* __restrict__ bfeat,
    const float* __restrict__ b_in,
    const float* __restrict__ W1, const float* __restrict__ b1,
    const float* __restrict__ W2, const float* __restrict__ b2,
    const float* __restrict__ W3, const float* __restrict__ b3,
    float* __restrict__ out)
{
    const int b = blockIdx.x;
    const int t = threadIdx.x;

    // tile (phase 0) and accs (phase 2) never live simultaneously
    __shared__ union {
        float tile[64][65];
        float accs[8 * 64 * 9];   // [wave][lane][8 neurons + pad]
    } sh;
    __shared__ int   sidx[MAXIDX];
    __shared__ int   scnt;
    __shared__ int   stile;
    __shared__ float l1s[L1];
    __shared__ float l2acc[L2];
    __shared__ float l2s[L2];
    __shared__ float l3s[L3_];

    int* claim_ctr = ctrs;        // offset 0
    int* done_ctr  = ctrs + 16;   // offset 64 B (separate line)

    if (t == 0) scnt = 0;

    // ---- Phase 0: work-stolen transpose tiles --------------------------
    int my = 0;
    for (;;) {
        if (t == 0) stile = atomicAdd(claim_ctr, 1);
        __syncthreads();                       // also publishes scnt=0
        const int tile_id = stile;
        if (tile_id >= NTILES) break;          // uniform exit
        ++my;
        const int jt = (tile_id % 1280) * 64;  // input-feature base
        const int ot = (tile_id / 1280) * 64;  // neuron base
        {   // read 64 neurons x 64 features: 16 lanes x v4f per row
            const int tx = t & 15, o = t >> 4; // o in 0..31
#pragma unroll
            for (int k = 0; k < 2; ++k) {
                const int oo = o + 32 * k;
                const v4f* p = (const v4f*)&W[(size_t)(ot + oo) * IN_TOTAL + jt + 4 * tx];
                v4f v = __builtin_nontemporal_load(p);
                sh.tile[4 * tx + 0][oo] = v.x;
                sh.tile[4 * tx + 1][oo] = v.y;
                sh.tile[4 * tx + 2][oo] = v.z;
                sh.tile[4 * tx + 3][oo] = v.w;
            }
        }
        __syncthreads();
        {   // write 64 feature rows x 64 fp16: 8 lanes x v8h per row
            const int j = t >> 3, c0 = (t & 7) * 8;
            v8f vf;
#pragma unroll
            for (int i = 0; i < 8; ++i) vf[i] = sh.tile[j][c0 + i];
            v8h h = __builtin_convertvector(vf, v8h);
            *(v8h*)&WTh[(size_t)(jt + j) * L1 + ot + c0] = h;
        }
        __syncthreads();                       // tile reuse safety
    }
    if (my > 0 && t == 0) {
        __threadfence();                       // flush WTh to device scope
        atomicAdd(done_ctr, my);
    }

    // ---- Phase 1: scan both perspective rows (values exactly 0.0/1.0) --
    const v4f* wrow = (const v4f*)(wf    + (size_t)b * IN_PER_SIDE);
    const v4f* brow = (const v4f*)(bfeat + (size_t)b * IN_PER_SIDE);
    const int nvec = IN_PER_SIDE / 4;  // 10240 float4 per side

    for (int i = t; i < nvec; i += 512) {
        v4f v = __builtin_nontemporal_load(wrow + i);
        if (v.x + v.y + v.z + v.w != 0.0f) {
            if (v.x != 0.0f) sidx[atomicAdd(&scnt, 1)] = 4 * i + 0;
            if (v.y != 0.0f) sidx[atomicAdd(&scnt, 1)] = 4 * i + 1;
            if (v.z != 0.0f) sidx[atomicAdd(&scnt, 1)] = 4 * i + 2;
            if (v.w != 0.0f) sidx[atomicAdd(&scnt, 1)] = 4 * i + 3;
        }
        v4f u = __builtin_nontemporal_load(brow + i);
        if (u.x + u.y + u.z + u.w != 0.0f) {
            if (u.x != 0.0f) sidx[atomicAdd(&scnt, 1)] = IN_PER_SIDE + 4 * i + 0;
            if (u.y != 0.0f) sidx[atomicAdd(&scnt, 1)] = IN_PER_SIDE + 4 * i + 1;
            if (u.z != 0.0f) sidx[atomicAdd(&scnt, 1)] = IN_PER_SIDE + 4 * i + 2;
            if (u.w != 0.0f) sidx[atomicAdd(&scnt, 1)] = IN_PER_SIDE + 4 * i + 3;
        }
    }

    // ---- Phase 1.5: wait for transpose completion (usually instant) ----
    if (t == 0) {
        while (__hip_atomic_load(done_ctr, __ATOMIC_RELAXED,
                                 __HIP_MEMORY_SCOPE_AGENT) < NTILES)
            __builtin_amdgcn_s_sleep(2);
        __threadfence();                       // invalidate stale L1/L2
    }
    __syncthreads();                           // also covers sidx/scnt

    // ---- Phase 2: gather active WTh columns; wave w, lane l ------------
    const int n = scnt;
    const int w = t >> 6;          // wave 0..7
    const int l = t & 63;          // lane 0..63
    const v8h* WTH8 = (const v8h*)WTh;   // feature f -> WTH8[f*64 + l]

    v8f acc0 = {0,0,0,0,0,0,0,0};
    v8f acc1 = {0,0,0,0,0,0,0,0};
    int k = w;
    for (; k + 16 <= n; k += 16) {
        v8h h0 = WTH8[(size_t)sidx[k]     * 64 + l];
        v8h h1 = WTH8[(size_t)sidx[k + 8] * 64 + l];
        acc0 += __builtin_convertvector(h0, v8f);
        acc1 += __builtin_convertvector(h1, v8f);
    }
    for (; k < n; k += 8)
        acc0 += __builtin_convertvector(WTH8[(size_t)sidx[k] * 64 + l], v8f);
    acc0 += acc1;

    {   // pad-9 stride: bank = (9*l + i) % 32, 9 odd -> conflict-free
        float* dst = &sh.accs[(w * 64 + l) * 9];
#pragma unroll
        for (int i = 0; i < 8; ++i) dst[i] = acc0[i];
    }
    __syncthreads();

    // ---- reduce waves + bias + clipped ReLU; thread t = neuron t -------
    {
        const int ll = t >> 3, c = t & 7;
        float s = 0.0f;
#pragma unroll
        for (int ww = 0; ww < 8; ++ww) s += sh.accs[(ww * 64 + ll) * 9 + c];
        l1s[t] = fminf(fmaxf(s + b_in[t], 0.0f), 1.0f);
    }
    __syncthreads();

    // ---- Phase 3: l2 = clip(l1 @ W1.T + b1): output k owned by 16 lanes
    {
        const int kk = t >> 4;
        const int gg = t & 15;
        const float* wp = W1 + (size_t)kk * L1;
        float p = 0.0f;
        for (int o = gg; o < L1; o += 16) p += wp[o] * l1s[o];
#pragma unroll
        for (int off = 8; off > 0; off >>= 1) p += __shfl_down(p, off, 16);
        if (gg == 0) l2acc[kk] = p;
    }
    __syncthreads();
    if (t < L2) l2s[t] = fminf(fmaxf(l2acc[t] + b1[t], 0.0f), 1.0f);
    __syncthreads();

    // ---- Phase 4: l3 = clip(l2 @ W2.T + b2), 32x32
    if (t < L3_) {
        const float* wp = W2 + (size_t)t * L2;
        float p = b2[t];
#pragma unroll
        for (int q = 0; q < L2; ++q) p += wp[q] * l2s[q];
        l3s[t] = fminf(fmaxf(p, 0.0f), 1.0f);
    }
    __syncthreads();

    // ---- Phase 5: out = l3 @ W3.T + b3
    if (t == 0) {
        float p = b3[0];
#pragma unroll
        for (int q = 0; q < L3_; ++q) p += W3[q] * l3s[q];
        out[b] = p;
    }
}

// ---------------------------------------------------------------------------
// Fallback (ws too small): fused kernel reading W_in columns directly.
// Correct but slow; not expected to run (ws ~2.5 GiB >> 84 MB).
// ---------------------------------------------------------------------------
__global__ __launch_bounds__(512) void nnue_fallback(
    const float* __restrict__ wf, const float* __restrict__ bfeat,
    const float* __restrict__ W_in, const float* __restrict__ b_in,
    const float* __restrict__ W1, const float* __restrict__ b1,
    const float* __restrict__ W2, const float* __restrict__ b2,
    const float* __restrict__ W3, const float* __restrict__ b3,
    float* __restrict__ out)
{
    const int b = blockIdx.x;
    const int t = threadIdx.x;
    __shared__ int   idxs[MAXIDX];
    __shared__ int   scnt;
    __shared__ float l1s[L1];
    __shared__ float l2acc[L2];
    __shared__ float l2s[L2];
    __shared__ float l3s[L3_];

    if (t == 0) scnt = 0;
    __syncthreads();
    const v4f* wrow = (const v4f*)(wf    + (size_t)b * IN_PER_SIDE);
    const v4f* brow = (const v4f*)(bfeat + (size_t)b * IN_PER_SIDE);
    for (int i = t; i < IN_PER_SIDE / 4; i += 512) {
        v4f v = wrow[i];
        if (v.x != 0.0f) idxs[atomicAdd(&scnt, 1)] = 4 * i + 0;
        if (v.y != 0.0f) idxs[atomicAdd(&scnt, 1)] = 4 * i + 1;
        if (v.z != 0.0f) idxs[atomicAdd(&scnt, 1)] = 4 * i + 2;
        if (v.w != 0.0f) idxs[atomicAdd(&scnt, 1)] = 4 * i + 3;
        v4f u = brow[i];
        if (u.x != 0.0f) idxs[atomicAdd(&scnt, 1)] = IN_PER_SIDE + 4 * i + 0;
        if (u.y != 0.0f) idxs[atomicAdd(&scnt, 1)] = IN_PER_SIDE + 4 * i + 1;
        if (u.z != 0.0f) idxs[atomicAdd(&scnt, 1)] = IN_PER_SIDE + 4 * i + 2;
        if (u.w != 0.0f) idxs[atomicAdd(&scnt, 1)] = IN_PER_SIDE + 4 * i + 3;
    }
    __syncthreads();
    const int n = scnt;
    float a0 = 0.0f;
    const float* row = W_in + (size_t)t * IN_TOTAL;
    for (int i = 0; i < n; ++i) a0 += row[idxs[i]];
    l1s[t] = fminf(fmaxf(b_in[t] + a0, 0.0f), 1.0f);
    __syncthreads();
    {
        const int k = t >> 4, g = t & 15;
        const float* wp = W1 + (size_t)k * L1;
        float p = 0.0f;
        for (int o = g; o < L1; o += 16) p += wp[o] * l1s[o];
#pragma unroll
        for (int off = 8; off > 0; off >>= 1) p += __shfl_down(p, off, 16);
        if (g == 0) l2acc[k] = p;
    }
    __syncthreads();
    if (t < L2) l2s[t] = fminf(fmaxf(l2acc[t] + b1[t], 0.0f), 1.0f);
    __syncthreads();
    if (t < L3_) {
        const float* wp = W2 + (size_t)t * L2;
        float p = b2[t];
#pragma unroll
        for (int q = 0; q < L2; ++q) p += wp[q] * l2s[q];
        l3s[t] = fminf(fmaxf(p, 0.0f), 1.0f);
    }
    __syncthreads();
    if (t == 0) {
        float p = b3[0];
#pragma unroll
        for (int q = 0; q < L3_; ++q) p += W3[q] * l3s[q];
        out[b] = p;
    }
}

extern "C" void kernel_launch(void* const* d_in, const int* in_sizes, int n_in,
                              void* d_out, int out_size, void* d_ws, size_t ws_size,
                              hipStream_t stream) {
    const float* wf   = (const float*)d_in[0];
    const float* bfeat= (const float*)d_in[1];
    const float* W_in = (const float*)d_in[2];
    const float* b_in = (const float*)d_in[3];
    const float* W1   = (const float*)d_in[4];
    const float* b1   = (const float*)d_in[5];
    const float* W2   = (const float*)d_in[6];
    const float* b2   = (const float*)d_in[7];
    const float* W3   = (const float*)d_in[8];
    const float* b3   = (const float*)d_in[9];
    float* out = (float*)d_out;

    if (ws_size >= WT_BYTES + CTR_BYTES) {
        _Float16* WTh = (_Float16*)d_ws;
        int* ctrs = (int*)((char*)d_ws + WT_BYTES);
        // ws is re-poisoned 0xAA before every call: zero claim/done counters
        hipMemsetAsync(ctrs, 0, CTR_BYTES, stream);
        nnue_all<<<BATCH, 512, 0, stream>>>(
            W_in, WTh, ctrs, wf, bfeat, b_in, W1, b1, W2, b2, W3, b3, out);
    } else {
        nnue_fallback<<<BATCH, 512, 0, stream>>>(
            wf, bfeat, W_in, b_in, W1, b1, W2, b2, W3, b3, out);
    }
}

// Round 8
// 1350.503 us; speedup vs baseline: 1.2033x; 1.2033x over previous
//
#include <hip/hip_runtime.h>
#include <hip/hip_bf16.h>

// Problem constants (from reference)
#define IN_PER_SIDE   40960
#define IN_TOTAL      81920     // 2 * 40960
#define L1            512
#define L2            32
#define L3_           32
#define BATCH         4096
#define MAXIDX        128       // per-row index capacity (~60 used)

// clang-native vectors (HIP float4 is a class; builtins reject it)
typedef float    v4f __attribute__((ext_vector_type(4)));
typedef float    v8f __attribute__((ext_vector_type(8)));
typedef _Float16 v8h __attribute__((ext_vector_type(8)));

// WT stored as fp16: 81920 * 512 * 2 B = 83.9 MB. |W_in| <= 0.0035 ->
// fp16 storage error gives output absmax ~1.2e-4 (measured R6), thr 4.6e-4.
#define WT_BYTES ((size_t)IN_TOTAL * L1 * sizeof(_Float16))

// ---------------------------------------------------------------------------
// Kernel 1: LDS-tiled transpose W_in [512, 81920] f32 -> WTh [81920, 512] f16.
// 64x64 tiles. Read: float4, nontemporal (W_in streamed once; keep L3 for
// WTh). Write: v8h = 16 B/lane, 8 lanes per feature row -> 128 B contiguous
// segments. All LDS access <=2-way bank alias (free on CDNA4; R6 measured 0).
// ---------------------------------------------------------------------------
__global__ __launch_bounds__(256) void transpose_win(
    const float* __restrict__ W, _Float16* __restrict__ WTh)
{
    __shared__ float tile[64][65];
    const int jt = blockIdx.x * 64;           // input-feature tile base
    const int ot = blockIdx.y * 64;           // output-neuron tile base
    const int t  = threadIdx.x;
    const int tx = t & 15;                    // float4 column
    const int ty = t >> 4;                    // row group

#pragma unroll
    for (int k = 0; k < 4; ++k) {
        const int o = ty + 16 * k;
        const v4f* p = (const v4f*)&W[(size_t)(ot + o) * IN_TOTAL + jt + 4 * tx];
        v4f v = __builtin_nontemporal_load(p);
        tile[4 * tx + 0][o] = v.x;
        tile[4 * tx + 1][o] = v.y;
        tile[4 * tx + 2][o] = v.z;
        tile[4 * tx + 3][o] = v.w;
    }
    __syncthreads();
    // write: slot s = j*8 + c (row j in 0..63, v8h chunk c in 0..7)
#pragma unroll
    for (int k = 0; k < 2; ++k) {
        const int s = t + 256 * k;
        const int j = s >> 3, c0 = (s & 7) * 8;
        v8f vf;
#pragma unroll
        for (int i = 0; i < 8; ++i) vf[i] = tile[j][c0 + i];
        v8h h = __builtin_convertvector(vf, v8h);
        *(v8h*)&WTh[(size_t)(jt + j) * L1 + ot + c0] = h;
    }
}

// ---------------------------------------------------------------------------
// Kernel 2: fused NNUE forward, one block per batch row, 512 threads.
//   Phase 1 (scan): regular (NOT nontemporal) float4 loads — the harness's
//       per-iteration input restore leaves the stream tail L3-resident
//       (R7 profile: FETCH 855 MB < 1.42 GB logical). Row halves processed
//       together: 4 independent 16 B loads in flight per lane, 10 iters.
//       {0,1} values -> sum test rejects all-zero vectors with one compare.
//   Phase 2 (gather): 8 waves x 64 lanes; one feature = 512 fp16 = 1 KB =
//       ONE wave64 x 16 B coalesced load (L3-resident). fp32 accumulate;
//       cross-wave reduce via pad-9 LDS (all accesses <=2-way = free).
//   Phase 3-5: tiny dense layers, shuffle reductions, no atomics.
// Scan (BW-bound) and gather (latency-bound) overlap across the 4096 blocks.
// ---------------------------------------------------------------------------
__global__ __launch_bounds__(512) void nnue_fused(
    const float* __restrict__ wf, const float* __restrict__ bfeat,
    const _Float16* __restrict__ WTh,
    const float* __restrict__ b_in,
    const float* __restrict__ W1, const float* __restrict__ b1,
    const float* __restrict__ W2, const float* __restrict__ b2,
    const float* __restrict__ W3, const float* __restrict__ b3,
    float* __restrict__ out)
{
    const int b = blockIdx.x;
    const int t = threadIdx.x;

    __shared__ int   sidx[MAXIDX];
    __shared__ int   scnt;
    __shared__ float accs[8 * 64 * 9];   // [wave][lane][8 neurons + pad]
    __shared__ float l1s[L1];
    __shared__ float l2acc[L2];
    __shared__ float l2s[L2];
    __shared__ float l3s[L3_];

    if (t == 0) scnt = 0;
    __syncthreads();

    // ---- Phase 1: scan both perspective rows (values are exactly 0.0/1.0)
    const v4f* wrow = (const v4f*)(wf    + (size_t)b * IN_PER_SIDE);
    const v4f* brow = (const v4f*)(bfeat + (size_t)b * IN_PER_SIDE);
    const int nvec = IN_PER_SIDE / 4;   // 10240 float4 per side
    const int half = nvec / 2;          // 5120

    for (int i = t; i < half; i += 512) {
        const int i2 = i + half;
        v4f w0 = wrow[i];
        v4f w1 = wrow[i2];
        v4f u0 = brow[i];
        v4f u1 = brow[i2];
        if (w0.x + w0.y + w0.z + w0.w != 0.0f) {
            if (w0.x != 0.0f) sidx[atomicAdd(&scnt, 1)] = 4 * i + 0;
            if (w0.y != 0.0f) sidx[atomicAdd(&scnt, 1)] = 4 * i + 1;
            if (w0.z != 0.0f) sidx[atomicAdd(&scnt, 1)] = 4 * i + 2;
            if (w0.w != 0.0f) sidx[atomicAdd(&scnt, 1)] = 4 * i + 3;
        }
        if (w1.x + w1.y + w1.z + w1.w != 0.0f) {
            if (w1.x != 0.0f) sidx[atomicAdd(&scnt, 1)] = 4 * i2 + 0;
            if (w1.y != 0.0f) sidx[atomicAdd(&scnt, 1)] = 4 * i2 + 1;
            if (w1.z != 0.0f) sidx[atomicAdd(&scnt, 1)] = 4 * i2 + 2;
            if (w1.w != 0.0f) sidx[atomicAdd(&scnt, 1)] = 4 * i2 + 3;
        }
        if (u0.x + u0.y + u0.z + u0.w != 0.0f) {
            if (u0.x != 0.0f) sidx[atomicAdd(&scnt, 1)] = IN_PER_SIDE + 4 * i + 0;
            if (u0.y != 0.0f) sidx[atomicAdd(&scnt, 1)] = IN_PER_SIDE + 4 * i + 1;
            if (u0.z != 0.0f) sidx[atomicAdd(&scnt, 1)] = IN_PER_SIDE + 4 * i + 2;
            if (u0.w != 0.0f) sidx[atomicAdd(&scnt, 1)] = IN_PER_SIDE + 4 * i + 3;
        }
        if (u1.x + u1.y + u1.z + u1.w != 0.0f) {
            if (u1.x != 0.0f) sidx[atomicAdd(&scnt, 1)] = IN_PER_SIDE + 4 * i2 + 0;
            if (u1.y != 0.0f) sidx[atomicAdd(&scnt, 1)] = IN_PER_SIDE + 4 * i2 + 1;
            if (u1.z != 0.0f) sidx[atomicAdd(&scnt, 1)] = IN_PER_SIDE + 4 * i2 + 2;
            if (u1.w != 0.0f) sidx[atomicAdd(&scnt, 1)] = IN_PER_SIDE + 4 * i2 + 3;
        }
    }
    __syncthreads();

    // ---- Phase 2: gather active WTh columns; wave w, lane l.
    const int n = scnt;
    const int w = t >> 6;          // wave 0..7
    const int l = t & 63;          // lane 0..63
    const v8h* WTH8 = (const v8h*)WTh;   // feature f -> WTH8[f*64 + l]

    v8f acc0 = {0,0,0,0,0,0,0,0};
    v8f acc1 = {0,0,0,0,0,0,0,0};
    int k = w;
    for (; k + 16 <= n; k += 16) {
        v8h h0 = WTH8[(size_t)sidx[k]     * 64 + l];
        v8h h1 = WTH8[(size_t)sidx[k + 8] * 64 + l];
        acc0 += __builtin_convertvector(h0, v8f);
        acc1 += __builtin_convertvector(h1, v8f);
    }
    for (; k < n; k += 8)
        acc0 += __builtin_convertvector(WTH8[(size_t)sidx[k] * 64 + l], v8f);
    acc0 += acc1;

    // scalar LDS stores at pad-9 stride: bank = (9*l + i) % 32, 9 odd ->
    // distinct over 32 lanes per i -> conflict-free.
    {
        float* dst = &accs[(w * 64 + l) * 9];
#pragma unroll
        for (int i = 0; i < 8; ++i) dst[i] = acc0[i];
    }
    __syncthreads();

    // ---- reduce waves + bias + clipped ReLU; thread t = neuron t.
    {
        const int ll = t >> 3, c = t & 7;
        float s = 0.0f;
#pragma unroll
        for (int ww = 0; ww < 8; ++ww) s += accs[(ww * 64 + ll) * 9 + c];
        l1s[t] = fminf(fmaxf(s + b_in[t], 0.0f), 1.0f);
    }
    __syncthreads();

    // ---- Phase 3: l2 = clip(l1 @ W1.T + b1): output k owned by 16 lanes
    {
        const int kk = t >> 4;
        const int gg = t & 15;
        const float* wp = W1 + (size_t)kk * L1;
        float p = 0.0f;
        for (int o = gg; o < L1; o += 16) p += wp[o] * l1s[o];
#pragma unroll
        for (int off = 8; off > 0; off >>= 1) p += __shfl_down(p, off, 16);
        if (gg == 0) l2acc[kk] = p;
    }
    __syncthreads();
    if (t < L2) l2s[t] = fminf(fmaxf(l2acc[t] + b1[t], 0.0f), 1.0f);
    __syncthreads();

    // ---- Phase 4: l3 = clip(l2 @ W2.T + b2), 32x32
    if (t < L3_) {
        const float* wp = W2 + (size_t)t * L2;
        float p = b2[t];
#pragma unroll
        for (int q = 0; q < L2; ++q) p += wp[q] * l2s[q];
        l3s[t] = fminf(fmaxf(p, 0.0f), 1.0f);
    }
    __syncthreads();

    // ---- Phase 5: out = l3 @ W3.T + b3
    if (t == 0) {
        float p = b3[0];
#pragma unroll
        for (int q = 0; q < L3_; ++q) p += W3[q] * l3s[q];
        out[b] = p;
    }
}

// ---------------------------------------------------------------------------
// Fallback (ws too small for WTh): fused kernel reading W_in columns
// directly. Correct but slow; not expected to run (ws ~2.5 GiB >> 84 MB).
// ---------------------------------------------------------------------------
__global__ __launch_bounds__(512) void nnue_fallback(
    const float* __restrict__ wf, const float* __restrict__ bfeat,
    const float* __restrict__ W_in, const float* __restrict__ b_in,
    const float* __restrict__ W1, const float* __restrict__ b1,
    const float* __restrict__ W2, const float* __restrict__ b2,
    const float* __restrict__ W3, const float* __restrict__ b3,
    float* __restrict__ out)
{
    const int b = blockIdx.x;
    const int t = threadIdx.x;
    __shared__ int   idxs[MAXIDX];
    __shared__ int   scnt;
    __shared__ float l1s[L1];
    __shared__ float l2acc[L2];
    __shared__ float l2s[L2];
    __shared__ float l3s[L3_];

    if (t == 0) scnt = 0;
    __syncthreads();
    const v4f* wrow = (const v4f*)(wf    + (size_t)b * IN_PER_SIDE);
    const v4f* brow = (const v4f*)(bfeat + (size_t)b * IN_PER_SIDE);
    for (int i = t; i < IN_PER_SIDE / 4; i += 512) {
        v4f v = wrow[i];
        if (v.x != 0.0f) idxs[atomicAdd(&scnt, 1)] = 4 * i + 0;
        if (v.y != 0.0f) idxs[atomicAdd(&scnt, 1)] = 4 * i + 1;
        if (v.z != 0.0f) idxs[atomicAdd(&scnt, 1)] = 4 * i + 2;
        if (v.w != 0.0f) idxs[atomicAdd(&scnt, 1)] = 4 * i + 3;
        v4f u = brow[i];
        if (u.x != 0.0f) idxs[atomicAdd(&scnt, 1)] = IN_PER_SIDE + 4 * i + 0;
        if (u.y != 0.0f) idxs[atomicAdd(&scnt, 1)] = IN_PER_SIDE + 4 * i + 1;
        if (u.z != 0.0f) idxs[atomicAdd(&scnt, 1)] = IN_PER_SIDE + 4 * i + 2;
        if (u.w != 0.0f) idxs[atomicAdd(&scnt, 1)] = IN_PER_SIDE + 4 * i + 3;
    }
    __syncthreads();
    const int n = scnt;
    float a0 = 0.0f;
    const float* row = W_in + (size_t)t * IN_TOTAL;
    for (int i = 0; i < n; ++i) a0 += row[idxs[i]];
    l1s[t] = fminf(fmaxf(b_in[t] + a0, 0.0f), 1.0f);
    __syncthreads();
    {
        const int k = t >> 4, g = t & 15;
        const float* wp = W1 + (size_t)k * L1;
        float p = 0.0f;
        for (int o = g; o < L1; o += 16) p += wp[o] * l1s[o];
#pragma unroll
        for (int off = 8; off > 0; off >>= 1) p += __shfl_down(p, off, 16);
        if (g == 0) l2acc[k] = p;
    }
    __syncthreads();
    if (t < L2) l2s[t] = fminf(fmaxf(l2acc[t] + b1[t], 0.0f), 1.0f);
    __syncthreads();
    if (t < L3_) {
        const float* wp = W2 + (size_t)t * L2;
        float p = b2[t];
#pragma unroll
        for (int q = 0; q < L2; ++q) p += wp[q] * l2s[q];
        l3s[t] = fminf(fmaxf(p, 0.0f), 1.0f);
    }
    __syncthreads();
    if (t == 0) {
        float p = b3[0];
#pragma unroll
        for (int q = 0; q < L3_; ++q) p += W3[q] * l3s[q];
        out[b] = p;
    }
}

extern "C" void kernel_launch(void* const* d_in, const int* in_sizes, int n_in,
                              void* d_out, int out_size, void* d_ws, size_t ws_size,
                              hipStream_t stream) {
    const float* wf   = (const float*)d_in[0];
    const float* bfeat= (const float*)d_in[1];
    const float* W_in = (const float*)d_in[2];
    const float* b_in = (const float*)d_in[3];
    const float* W1   = (const float*)d_in[4];
    const float* b1   = (const float*)d_in[5];
    const float* W2   = (const float*)d_in[6];
    const float* b2   = (const float*)d_in[7];
    const float* W3   = (const float*)d_in[8];
    const float* b3   = (const float*)d_in[9];
    float* out = (float*)d_out;

    if (ws_size >= WT_BYTES) {
        _Float16* WTh = (_Float16*)d_ws;
        dim3 grid(IN_TOTAL / 64, L1 / 64);   // (1280, 8)
        transpose_win<<<grid, 256, 0, stream>>>(W_in, WTh);
        nnue_fused<<<BATCH, 512, 0, stream>>>(
            wf, bfeat, WTh, b_in, W1, b1, W2, b2, W3, b3, out);
    } else {
        nnue_fallback<<<BATCH, 512, 0, stream>>>(
            wf, bfeat, W_in, b_in, W1, b1, W2, b2, W3, b3, out);
    }
}